// Round 3
// baseline (2188.144 us; speedup 1.0000x reference)
//
#include <hip/hip_runtime.h>
#include <cstdint>
#include <cstddef>

#define B_ 4
#define S_ 2048
#define E_ 2048
#define H_ 16
#define DH_ 128
#define F_ 8192
#define NTOK (B_*S_)
#define QKVN (3*E_)

typedef __attribute__((ext_vector_type(4))) float f32x4;
typedef __attribute__((ext_vector_type(8))) __bf16 bf16x8;
typedef __attribute__((ext_vector_type(8))) short s16x8;
typedef __attribute__((ext_vector_type(4))) short s16x4;

using gas_ptr = const __attribute__((address_space(1))) void*;
using las_ptr = __attribute__((address_space(3))) void*;

__device__ __forceinline__ short f2bf(float f) {
  union { float f; uint32_t u; } v{f};
  uint32_t r = v.u + 0x7FFFu + ((v.u >> 16) & 1u);   // round-to-nearest-even
  return (short)(r >> 16);
}
__device__ __forceinline__ float bf2f(short s) {
  union { uint32_t u; float f; } v;
  v.u = ((uint32_t)(uint16_t)s) << 16;
  return v.f;
}

// ---------------- RMSNorm + RoPE -> bf16 ----------------
__global__ __launch_bounds__(256) void k_rms_rope(const float* __restrict__ x,
                                                  const float* __restrict__ gamma,
                                                  const int* __restrict__ pos,
                                                  short* __restrict__ y) {
  const int row = blockIdx.x;
  const int s = row & (S_ - 1);
  const int t = threadIdx.x;
  const int head = t >> 4;
  const int j0 = (t & 15) << 2;
  const float* xr = x + (size_t)row * E_;
  const int c1 = head * DH_ + j0;
  const int c2 = c1 + 64;
  f32x4 x1 = *(const f32x4*)(xr + c1);
  f32x4 x2 = *(const f32x4*)(xr + c2);
  float ss = x1[0]*x1[0]+x1[1]*x1[1]+x1[2]*x1[2]+x1[3]*x1[3]
           + x2[0]*x2[0]+x2[1]*x2[1]+x2[2]*x2[2]+x2[3]*x2[3];
  #pragma unroll
  for (int off = 32; off >= 1; off >>= 1) ss += __shfl_xor(ss, off, 64);
  __shared__ float red[4];
  __shared__ float rsh;
  if ((t & 63) == 0) red[t >> 6] = ss;
  __syncthreads();
  if (t == 0) rsh = rsqrtf((red[0]+red[1]+red[2]+red[3]) * (1.0f / E_) + 1e-5f);
  __syncthreads();
  const float r = rsh;
  f32x4 g1 = *(const f32x4*)(gamma + c1);
  f32x4 g2 = *(const f32x4*)(gamma + c2);
  const float p = (float)pos[s];
  s16x4 o1, o2;
  #pragma unroll
  for (int jj = 0; jj < 4; ++jj) {
    float fi = exp2f((float)(j0 + jj) * (-13.287712379549449f / 64.0f));
    float ang = p * fi;
    float sn, cs;
    sincosf(ang, &sn, &cs);
    float a = x1[jj] * r * g1[jj];
    float b = x2[jj] * r * g2[jj];
    o1[jj] = f2bf(a * cs - b * sn);
    o2[jj] = f2bf(b * cs + a * sn);
  }
  *(s16x4*)(y + (size_t)row * E_ + c1) = o1;
  *(s16x4*)(y + (size_t)row * E_ + c2) = o2;
}

// ---------------- RMSNorm (no rope), fp32 in -> bf16 ----------------
__global__ __launch_bounds__(256) void k_rms(const float* __restrict__ x,
                                             const float* __restrict__ gamma,
                                             short* __restrict__ y) {
  const int row = blockIdx.x;
  const int t = threadIdx.x;
  const int c = t << 3;
  const float* xr = x + (size_t)row * E_;
  f32x4 a = *(const f32x4*)(xr + c);
  f32x4 b = *(const f32x4*)(xr + c + 4);
  float ss = a[0]*a[0]+a[1]*a[1]+a[2]*a[2]+a[3]*a[3]
           + b[0]*b[0]+b[1]*b[1]+b[2]*b[2]+b[3]*b[3];
  #pragma unroll
  for (int off = 32; off >= 1; off >>= 1) ss += __shfl_xor(ss, off, 64);
  __shared__ float red[4];
  __shared__ float rsh;
  if ((t & 63) == 0) red[t >> 6] = ss;
  __syncthreads();
  if (t == 0) rsh = rsqrtf((red[0]+red[1]+red[2]+red[3]) * (1.0f / E_) + 1e-5f);
  __syncthreads();
  const float r = rsh;
  f32x4 ga = *(const f32x4*)(gamma + c);
  f32x4 gb = *(const f32x4*)(gamma + c + 4);
  s16x8 o;
  #pragma unroll
  for (int jj = 0; jj < 4; ++jj) {
    o[jj]   = f2bf(a[jj] * r * ga[jj]);
    o[4+jj] = f2bf(b[jj] * r * gb[jj]);
  }
  *(s16x8*)(y + (size_t)row * E_ + c) = o;
}

// ---------------- fp32 (R,C) -> bf16 (C,R) transpose ----------------
__global__ __launch_bounds__(256) void k_transpose_f32_bf16(const float* __restrict__ src,
                                                            short* __restrict__ dst,
                                                            int R, int C) {
  __shared__ float tile[32][33];
  const int c0 = blockIdx.x << 5, r0 = blockIdx.y << 5;
  const int tx = threadIdx.x & 31, ty = threadIdx.x >> 5;
  #pragma unroll
  for (int j = 0; j < 32; j += 8)
    tile[ty + j][tx] = src[(size_t)(r0 + ty + j) * C + c0 + tx];
  __syncthreads();
  #pragma unroll
  for (int j = 0; j < 32; j += 8)
    dst[(size_t)(c0 + ty + j) * R + r0 + tx] = f2bf(tile[tx][ty + j]);
}

// ---------------- V section of QKV -> per-(b,h) V^T (bf16) ----------------
__global__ __launch_bounds__(256) void k_transpose_v(const short* __restrict__ qkv,
                                                     short* __restrict__ vt) {
  __shared__ short tile[32][33];
  const int bh = blockIdx.z;
  const short* src = qkv + (size_t)(bh >> 4) * S_ * QKVN + 2 * E_ + (bh & 15) * DH_;
  short* dst = vt + (size_t)bh * DH_ * S_;
  const int s0 = blockIdx.x << 5, d0 = blockIdx.y << 5;
  const int tx = threadIdx.x & 31, ty = threadIdx.x >> 5;
  #pragma unroll
  for (int j = 0; j < 32; j += 8)
    tile[ty + j][tx] = src[(size_t)(s0 + ty + j) * QKVN + d0 + tx];
  __syncthreads();
  #pragma unroll
  for (int j = 0; j < 32; j += 8)
    dst[(size_t)(d0 + ty + j) * S_ + s0 + tx] = tile[tx][ty + j];
}

// ---------------- m97-style bf16 GEMM: C[M,N] = A[M,K] * Bt[N,K]^T ----------------
// EPI: 0 = bf16 store, 1 = fp32 store + fp32 residual(aux), 2 = exact-GELU -> bf16,
//      3 = multiply by existing bf16 in C -> bf16
// Supertile swizzle: 16-M-tile-tall bands, N advances within a band, so the
// ~512 concurrently-resident blocks touch ~16 A-panels + ~32 B-panels (~24 MB)
// instead of the full B matrix — keeps global_load_lds hitting L2/LLC.
template<int EPI>
__global__ __launch_bounds__(256, 3) void k_gemm(const short* __restrict__ A,
                                                 const short* __restrict__ Bt,
                                                 void* Cv, const void* aux,
                                                 int M, int N, int K) {
  __shared__ short As[128 * 64];
  __shared__ short Bs[128 * 64];
  const int tiles_n = gridDim.x, tiles_m = gridDim.y;
  {
    // nothing
  }
  const int bid = blockIdx.y * tiles_n + blockIdx.x;
  const int GM = 16;
  const int band = bid / (GM * tiles_n);
  const int first_m = band * GM;
  const int bandh = min(GM, tiles_m - first_m);
  const int rem = bid - band * GM * tiles_n;
  const int m_tile = first_m + rem % bandh;
  const int n_tile = rem / bandh;
  const int n0 = n_tile << 7, m0 = m_tile << 7;

  const int tid = threadIdx.x;
  const int wave = tid >> 6, lane = tid & 63;
  const int ll = lane & 15, lh = lane >> 4;
  const int wm = wave >> 1, wn = wave & 1;
  const int lr = lane >> 3, lc = lane & 7;
  const short* Ag = A  + (size_t)(m0 + wave * 32 + lr) * K + lc * 8;
  const short* Bg = Bt + (size_t)(n0 + wave * 32 + lr) * K + lc * 8;
  const f32x4 fzero = {0.f, 0.f, 0.f, 0.f};
  f32x4 acc[4][4];
  #pragma unroll
  for (int i = 0; i < 4; ++i)
    #pragma unroll
    for (int j = 0; j < 4; ++j) acc[i][j] = fzero;

  for (int k0 = 0; k0 < K; k0 += 64) {
    __syncthreads();
    #pragma unroll
    for (int i = 0; i < 4; ++i) {
      __builtin_amdgcn_global_load_lds((gas_ptr)(Ag + (size_t)(i * 8) * K),
                                       (las_ptr)&As[(wave * 32 + i * 8) * 64], 16, 0, 0);
      __builtin_amdgcn_global_load_lds((gas_ptr)(Bg + (size_t)(i * 8) * K),
                                       (las_ptr)&Bs[(wave * 32 + i * 8) * 64], 16, 0, 0);
    }
    Ag += 64; Bg += 64;
    __syncthreads();
    #pragma unroll
    for (int kc = 0; kc < 2; ++kc) {
      bf16x8 af[4], bfr[4];
      #pragma unroll
      for (int mt = 0; mt < 4; ++mt)
        af[mt] = *(const bf16x8*)&As[(wm * 64 + mt * 16 + ll) * 64 + kc * 32 + lh * 8];
      #pragma unroll
      for (int nt = 0; nt < 4; ++nt)
        bfr[nt] = *(const bf16x8*)&Bs[(wn * 64 + nt * 16 + ll) * 64 + kc * 32 + lh * 8];
      #pragma unroll
      for (int mt = 0; mt < 4; ++mt)
        #pragma unroll
        for (int nt = 0; nt < 4; ++nt)
          acc[mt][nt] = __builtin_amdgcn_mfma_f32_16x16x32_bf16(af[mt], bfr[nt], acc[mt][nt], 0, 0, 0);
    }
  }
  // epilogue; verified C/D layout: col = lane&15, row = (lane>>4)*4 + reg
  #pragma unroll
  for (int mt = 0; mt < 4; ++mt) {
    const int row = m0 + wm * 64 + mt * 16 + lh * 4;
    #pragma unroll
    for (int nt = 0; nt < 4; ++nt) {
      const int col = n0 + wn * 64 + nt * 16 + ll;
      #pragma unroll
      for (int rg = 0; rg < 4; ++rg) {
        const float c = acc[mt][nt][rg];
        const size_t idx = (size_t)(row + rg) * N + col;
        if constexpr (EPI == 0) {
          ((short*)Cv)[idx] = f2bf(c);
        } else if constexpr (EPI == 1) {
          ((float*)Cv)[idx] = c + ((const float*)aux)[idx];
        } else if constexpr (EPI == 2) {
          float g = 0.5f * c * (1.0f + erff(c * 0.70710678118654752f));
          ((short*)Cv)[idx] = f2bf(g);
        } else {
          float g = bf2f(((short*)Cv)[idx]);
          ((short*)Cv)[idx] = f2bf(c * g);
        }
      }
    }
  }
}

// ---------------- flash attention ----------------
#define CEXP 0.12752682475470602f   // log2(e)/sqrt(128)
__global__ __launch_bounds__(256, 2) void k_flash(const short* __restrict__ qkv,
                                                  const short* __restrict__ vt,
                                                  short* __restrict__ attn) {
  __shared__ short Kt[64][136];
  __shared__ short VtT[128][72];
  __shared__ short Pt[4][32][72];
  const int qt = blockIdx.x, bh = blockIdx.y;
  const int b = bh >> 4, h = bh & 15;
  const int q0 = qt << 7;
  const int tid = threadIdx.x, wave = tid >> 6, lane = tid & 63;
  const int ll = lane & 15, lh = lane >> 4;
  const short* qbase = qkv + (size_t)b * S_ * QKVN + h * DH_;
  const short* kbase = qbase + E_;
  const short* vbase = vt + (size_t)bh * DH_ * S_;

  bf16x8 qf[2][4];
  #pragma unroll
  for (int mt = 0; mt < 2; ++mt) {
    const short* qr = qbase + (size_t)(q0 + wave * 32 + mt * 16 + ll) * QKVN;
    #pragma unroll
    for (int kc = 0; kc < 4; ++kc) qf[mt][kc] = *(const bf16x8*)(qr + kc * 32 + lh * 8);
  }

  const f32x4 fzero = {0.f, 0.f, 0.f, 0.f};
  float m_i[2][4], l_i[2][4];
  f32x4 oacc[2][8];
  #pragma unroll
  for (int mt = 0; mt < 2; ++mt) {
    #pragma unroll
    for (int rg = 0; rg < 4; ++rg) { m_i[mt][rg] = -1e30f; l_i[mt][rg] = 0.f; }
    #pragma unroll
    for (int n8 = 0; n8 < 8; ++n8) oacc[mt][n8] = fzero;
  }

  const int nkt = (q0 + 128) >> 6;
  for (int kt = 0; kt < nkt; ++kt) {
    const int k0 = kt << 6;
    __syncthreads();
    #pragma unroll
    for (int p = 0; p < 4; ++p) {
      int idx = p * 256 + tid;
      int r = idx >> 4, c0 = (idx & 15) << 3;
      *(s16x8*)&Kt[r][c0] = *(const s16x8*)(kbase + (size_t)(k0 + r) * QKVN + c0);
      int dh = idx >> 3, kk = (idx & 7) << 3;
      *(s16x8*)&VtT[dh][kk] = *(const s16x8*)(vbase + (size_t)dh * S_ + k0 + kk);
    }
    __syncthreads();

    f32x4 sc[2][4];
    #pragma unroll
    for (int mt = 0; mt < 2; ++mt)
      #pragma unroll
      for (int nt = 0; nt < 4; ++nt) sc[mt][nt] = fzero;
    #pragma unroll
    for (int kc = 0; kc < 4; ++kc) {
      bf16x8 kb[4];
      #pragma unroll
      for (int nt = 0; nt < 4; ++nt)
        kb[nt] = *(const bf16x8*)&Kt[nt * 16 + ll][kc * 32 + lh * 8];
      #pragma unroll
      for (int mt = 0; mt < 2; ++mt)
        #pragma unroll
        for (int nt = 0; nt < 4; ++nt)
          sc[mt][nt] = __builtin_amdgcn_mfma_f32_16x16x32_bf16(qf[mt][kc], kb[nt], sc[mt][nt], 0, 0, 0);
    }

    if (k0 + 63 > q0) {
      #pragma unroll
      for (int mt = 0; mt < 2; ++mt)
        #pragma unroll
        for (int nt = 0; nt < 4; ++nt)
          #pragma unroll
          for (int rg = 0; rg < 4; ++rg) {
            int kidx = k0 + nt * 16 + ll;
            int qidx = q0 + wave * 32 + mt * 16 + lh * 4 + rg;
            if (kidx > qidx) sc[mt][nt][rg] = -1e30f;
          }
    }

    #pragma unroll
    for (int mt = 0; mt < 2; ++mt)
      #pragma unroll
      for (int rg = 0; rg < 4; ++rg) {
        float mx = fmaxf(fmaxf(sc[mt][0][rg], sc[mt][1][rg]),
                         fmaxf(sc[mt][2][rg], sc[mt][3][rg]));
        #pragma unroll
        for (int off = 1; off < 16; off <<= 1) mx = fmaxf(mx, __shfl_xor(mx, off, 64));
        float mn = fmaxf(m_i[mt][rg], mx);
        float al = exp2f((m_i[mt][rg] - mn) * CEXP);
        m_i[mt][rg] = mn;
        float rsum = 0.f;
        #pragma unroll
        for (int nt = 0; nt < 4; ++nt) {
          float pv = exp2f((sc[mt][nt][rg] - mn) * CEXP);
          sc[mt][nt][rg] = pv;
          rsum += pv;
        }
        #pragma unroll
        for (int off = 1; off < 16; off <<= 1) rsum += __shfl_xor(rsum, off, 64);
        l_i[mt][rg] = l_i[mt][rg] * al + rsum;
        #pragma unroll
        for (int n8 = 0; n8 < 8; ++n8) oacc[mt][n8][rg] *= al;
      }

    #pragma unroll
    for (int mt = 0; mt < 2; ++mt)
      #pragma unroll
      for (int nt = 0; nt < 4; ++nt)
        #pragma unroll
        for (int rg = 0; rg < 4; ++rg)
          Pt[wave][mt * 16 + lh * 4 + rg][nt * 16 + ll] = f2bf(sc[mt][nt][rg]);

    #pragma unroll
    for (int kc2 = 0; kc2 < 2; ++kc2) {
      bf16x8 pa[2];
      #pragma unroll
      for (int mt = 0; mt < 2; ++mt)
        pa[mt] = *(const bf16x8*)&Pt[wave][mt * 16 + ll][kc2 * 32 + lh * 8];
      #pragma unroll
      for (int n8 = 0; n8 < 8; ++n8) {
        bf16x8 vb = *(const bf16x8*)&VtT[n8 * 16 + ll][kc2 * 32 + lh * 8];
        #pragma unroll
        for (int mt = 0; mt < 2; ++mt)
          oacc[mt][n8] = __builtin_amdgcn_mfma_f32_16x16x32_bf16(pa[mt], vb, oacc[mt][n8], 0, 0, 0);
      }
    }
  }

  short* ab = attn + (size_t)(b * S_) * E_ + h * DH_;
  #pragma unroll
  for (int mt = 0; mt < 2; ++mt) {
    const int row = q0 + wave * 32 + mt * 16 + lh * 4;
    #pragma unroll
    for (int n8 = 0; n8 < 8; ++n8) {
      const int col = n8 * 16 + ll;
      #pragma unroll
      for (int rg = 0; rg < 4; ++rg)
        ab[(size_t)(row + rg) * E_ + col] = f2bf(oacc[mt][n8][rg] / l_i[mt][rg]);
    }
  }
}

// ---------------- launch ----------------
// Workspace plan (192 MiB; single stream => lifetime-disjoint aliasing is safe):
//   W slot   [ 33,554,432 B]  each weight transposed here right before its GEMM
//   big slot [134,217,728 B]  phase 1: QKV | VT; phase 2: Hb
//   act slot [ 33,554,432 B]  Y1 -> ATTN -> Y2
//   X2 (fp32 residual stream) lives in d_out, overwritten by the final GEMM.
extern "C" void kernel_launch(void* const* d_in, const int* in_sizes, int n_in,
                              void* d_out, int out_size, void* d_ws, size_t ws_size,
                              hipStream_t stream) {
  (void)in_sizes; (void)n_in; (void)out_size; (void)ws_size;
  const float* x      = (const float*)d_in[0];
  const float* g_attn = (const float*)d_in[1];
  const float* g_ffn  = (const float*)d_in[2];
  const float* wq     = (const float*)d_in[3];
  const float* wk     = (const float*)d_in[4];
  const float* wv     = (const float*)d_in[5];
  const float* wo     = (const float*)d_in[6];
  const float* wg     = (const float*)d_in[7];
  const float* wl     = (const float*)d_in[8];
  const float* wout   = (const float*)d_in[9];
  const int*   pos    = (const int*)d_in[10];

  char* wsb = (char*)d_ws;
  short* W    = (short*)wsb;
  short* BIG  = (short*)(wsb + (size_t)33554432);
  short* ACT  = (short*)(wsb + (size_t)33554432 + 134217728);

  short* QKV  = BIG;
  short* VT   = BIG + (size_t)NTOK * QKVN;
  short* Hb   = BIG;
  short* Y1   = ACT;
  short* ATTN = ACT;
  short* Y2   = ACT;
  float* X2   = (float*)d_out;

  const dim3 blk(256);

  k_transpose_f32_bf16<<<dim3(64, 64), blk, 0, stream>>>(wq, W,                   2048, 2048);
  k_transpose_f32_bf16<<<dim3(64, 64), blk, 0, stream>>>(wk, W + 2048 * 2048,     2048, 2048);
  k_transpose_f32_bf16<<<dim3(64, 64), blk, 0, stream>>>(wv, W + 2 * 2048 * 2048, 2048, 2048);

  k_rms_rope<<<NTOK, blk, 0, stream>>>(x, g_attn, pos, Y1);
  k_gemm<0><<<dim3(QKVN / 128, NTOK / 128), blk, 0, stream>>>(Y1, W, QKV, nullptr, NTOK, QKVN, E_);
  k_transpose_v<<<dim3(S_ / 32, DH_ / 32, B_ * H_), blk, 0, stream>>>(QKV, VT);
  k_flash<<<dim3(S_ / 128, B_ * H_), blk, 0, stream>>>(QKV, VT, ATTN);

  k_transpose_f32_bf16<<<dim3(64, 64), blk, 0, stream>>>(wo, W, 2048, 2048);
  k_gemm<1><<<dim3(E_ / 128, NTOK / 128), blk, 0, stream>>>(ATTN, W, X2, x, NTOK, E_, E_);

  k_rms<<<NTOK, blk, 0, stream>>>(X2, g_ffn, Y2);

  k_transpose_f32_bf16<<<dim3(256, 64), blk, 0, stream>>>(wg, W, 2048, 8192);
  k_gemm<2><<<dim3(F_ / 128, NTOK / 128), blk, 0, stream>>>(Y2, W, Hb, nullptr, NTOK, F_, E_);
  k_transpose_f32_bf16<<<dim3(256, 64), blk, 0, stream>>>(wl, W, 2048, 8192);
  k_gemm<3><<<dim3(F_ / 128, NTOK / 128), blk, 0, stream>>>(Y2, W, Hb, nullptr, NTOK, F_, E_);
  k_transpose_f32_bf16<<<dim3(64, 256), blk, 0, stream>>>(wout, W, 8192, 2048);
  k_gemm<1><<<dim3(E_ / 128, NTOK / 128), blk, 0, stream>>>(Hb, W, d_out, X2, NTOK, E_, F_);
}

// Round 4
// 1851.659 us; speedup vs baseline: 1.1817x; 1.1817x over previous
//
#include <hip/hip_runtime.h>
#include <cstdint>
#include <cstddef>

#define B_ 4
#define S_ 2048
#define E_ 2048
#define H_ 16
#define DH_ 128
#define F_ 8192
#define NTOK (B_*S_)
#define QKVN (3*E_)

typedef __attribute__((ext_vector_type(4))) float f32x4;
typedef __attribute__((ext_vector_type(8))) __bf16 bf16x8;
typedef __attribute__((ext_vector_type(8))) short s16x8;
typedef __attribute__((ext_vector_type(4))) short s16x4;

using gas_ptr = const __attribute__((address_space(1))) void*;
using las_ptr = __attribute__((address_space(3))) void*;

__device__ __forceinline__ short f2bf(float f) {
  union { float f; uint32_t u; } v{f};
  uint32_t r = v.u + 0x7FFFu + ((v.u >> 16) & 1u);   // round-to-nearest-even
  return (short)(r >> 16);
}
__device__ __forceinline__ float bf2f(short s) {
  union { uint32_t u; float f; } v;
  v.u = ((uint32_t)(uint16_t)s) << 16;
  return v.f;
}

// ---------------- RMSNorm + RoPE -> bf16 ----------------
__global__ __launch_bounds__(256) void k_rms_rope(const float* __restrict__ x,
                                                  const float* __restrict__ gamma,
                                                  const int* __restrict__ pos,
                                                  short* __restrict__ y) {
  const int row = blockIdx.x;
  const int s = row & (S_ - 1);
  const int t = threadIdx.x;
  const int head = t >> 4;
  const int j0 = (t & 15) << 2;
  const float* xr = x + (size_t)row * E_;
  const int c1 = head * DH_ + j0;
  const int c2 = c1 + 64;
  f32x4 x1 = *(const f32x4*)(xr + c1);
  f32x4 x2 = *(const f32x4*)(xr + c2);
  float ss = x1[0]*x1[0]+x1[1]*x1[1]+x1[2]*x1[2]+x1[3]*x1[3]
           + x2[0]*x2[0]+x2[1]*x2[1]+x2[2]*x2[2]+x2[3]*x2[3];
  #pragma unroll
  for (int off = 32; off >= 1; off >>= 1) ss += __shfl_xor(ss, off, 64);
  __shared__ float red[4];
  __shared__ float rsh;
  if ((t & 63) == 0) red[t >> 6] = ss;
  __syncthreads();
  if (t == 0) rsh = rsqrtf((red[0]+red[1]+red[2]+red[3]) * (1.0f / E_) + 1e-5f);
  __syncthreads();
  const float r = rsh;
  f32x4 g1 = *(const f32x4*)(gamma + c1);
  f32x4 g2 = *(const f32x4*)(gamma + c2);
  const float p = (float)pos[s];
  s16x4 o1, o2;
  #pragma unroll
  for (int jj = 0; jj < 4; ++jj) {
    float fi = exp2f((float)(j0 + jj) * (-13.287712379549449f / 64.0f));
    float ang = p * fi;
    float sn, cs;
    sincosf(ang, &sn, &cs);
    float a = x1[jj] * r * g1[jj];
    float b = x2[jj] * r * g2[jj];
    o1[jj] = f2bf(a * cs - b * sn);
    o2[jj] = f2bf(b * cs + a * sn);
  }
  *(s16x4*)(y + (size_t)row * E_ + c1) = o1;
  *(s16x4*)(y + (size_t)row * E_ + c2) = o2;
}

// ---------------- RMSNorm (no rope), fp32 in -> bf16 ----------------
__global__ __launch_bounds__(256) void k_rms(const float* __restrict__ x,
                                             const float* __restrict__ gamma,
                                             short* __restrict__ y) {
  const int row = blockIdx.x;
  const int t = threadIdx.x;
  const int c = t << 3;
  const float* xr = x + (size_t)row * E_;
  f32x4 a = *(const f32x4*)(xr + c);
  f32x4 b = *(const f32x4*)(xr + c + 4);
  float ss = a[0]*a[0]+a[1]*a[1]+a[2]*a[2]+a[3]*a[3]
           + b[0]*b[0]+b[1]*b[1]+b[2]*b[2]+b[3]*b[3];
  #pragma unroll
  for (int off = 32; off >= 1; off >>= 1) ss += __shfl_xor(ss, off, 64);
  __shared__ float red[4];
  __shared__ float rsh;
  if ((t & 63) == 0) red[t >> 6] = ss;
  __syncthreads();
  if (t == 0) rsh = rsqrtf((red[0]+red[1]+red[2]+red[3]) * (1.0f / E_) + 1e-5f);
  __syncthreads();
  const float r = rsh;
  f32x4 ga = *(const f32x4*)(gamma + c);
  f32x4 gb = *(const f32x4*)(gamma + c + 4);
  s16x8 o;
  #pragma unroll
  for (int jj = 0; jj < 4; ++jj) {
    o[jj]   = f2bf(a[jj] * r * ga[jj]);
    o[4+jj] = f2bf(b[jj] * r * gb[jj]);
  }
  *(s16x8*)(y + (size_t)row * E_ + c) = o;
}

// ---------------- fp32 (R,C) -> bf16 (C,R) transpose ----------------
__global__ __launch_bounds__(256) void k_transpose_f32_bf16(const float* __restrict__ src,
                                                            short* __restrict__ dst,
                                                            int R, int C) {
  __shared__ float tile[32][33];
  const int c0 = blockIdx.x << 5, r0 = blockIdx.y << 5;
  const int tx = threadIdx.x & 31, ty = threadIdx.x >> 5;
  #pragma unroll
  for (int j = 0; j < 32; j += 8)
    tile[ty + j][tx] = src[(size_t)(r0 + ty + j) * C + c0 + tx];
  __syncthreads();
  #pragma unroll
  for (int j = 0; j < 32; j += 8)
    dst[(size_t)(c0 + ty + j) * R + r0 + tx] = f2bf(tile[tx][ty + j]);
}

// ---------------- V section of QKV -> per-(b,h) V^T (bf16) ----------------
__global__ __launch_bounds__(256) void k_transpose_v(const short* __restrict__ qkv,
                                                     short* __restrict__ vt) {
  __shared__ short tile[32][33];
  const int bh = blockIdx.z;
  const short* src = qkv + (size_t)(bh >> 4) * S_ * QKVN + 2 * E_ + (bh & 15) * DH_;
  short* dst = vt + (size_t)bh * DH_ * S_;
  const int s0 = blockIdx.x << 5, d0 = blockIdx.y << 5;
  const int tx = threadIdx.x & 31, ty = threadIdx.x >> 5;
  #pragma unroll
  for (int j = 0; j < 32; j += 8)
    tile[ty + j][tx] = src[(size_t)(s0 + ty + j) * QKVN + d0 + tx];
  __syncthreads();
  #pragma unroll
  for (int j = 0; j < 32; j += 8)
    dst[(size_t)(d0 + ty + j) * S_ + s0 + tx] = tile[tx][ty + j];
}

// ---------------- m97-style bf16 GEMM: C[M,N] = A[M,K] * Bt[N,K]^T ----------------
// EPI: 0 = bf16 store, 1 = fp32 store + fp32 residual(aux), 2 = exact-GELU -> bf16,
//      3 = multiply by existing bf16 in C -> bf16
// LDS XOR bank swizzle: row stride is 128 B (= all 32 banks), so unswizzled reads
// have a row-independent bank index -> 16 banks idle, ~2x LDS slowdown (measured
// 1.0e8 SQ_LDS_BANK_CONFLICT/dispatch in r2). global_load_lds forces dest =
// base + lane*16, so we permute the SOURCE: lane (lr,lc) fetches colgroup lc^lr,
// i.e. LDS (row, pcg) holds global colgroup pcg ^ (row&7). Readers xor with
// (ll&7); every ds_read_b128 then touches all 32 banks, <=2 lanes/address.
template<int EPI>
__global__ __launch_bounds__(256, 3) void k_gemm(const short* __restrict__ A,
                                                 const short* __restrict__ Bt,
                                                 void* Cv, const void* aux,
                                                 int M, int N, int K) {
  __shared__ short As[128 * 64];
  __shared__ short Bs[128 * 64];
  const int tiles_n = gridDim.x, tiles_m = gridDim.y;
  const int bid = blockIdx.y * tiles_n + blockIdx.x;
  const int GM = 16;
  const int band = bid / (GM * tiles_n);
  const int first_m = band * GM;
  const int bandh = min(GM, tiles_m - first_m);
  const int rem = bid - band * GM * tiles_n;
  const int m_tile = first_m + rem % bandh;
  const int n_tile = rem / bandh;
  const int n0 = n_tile << 7, m0 = m_tile << 7;

  const int tid = threadIdx.x;
  const int wave = tid >> 6, lane = tid & 63;
  const int ll = lane & 15, lh = lane >> 4;
  const int wm = wave >> 1, wn = wave & 1;
  const int lr = lane >> 3, lc = lane & 7;
  const int lcs = lc ^ lr;                     // XOR-swizzled source colgroup
  const short* Ag = A  + (size_t)(m0 + wave * 32 + lr) * K + lcs * 8;
  const short* Bg = Bt + (size_t)(n0 + wave * 32 + lr) * K + lcs * 8;
  const int sw = ll & 7;                       // reader-side xor (= row & 7)
  const f32x4 fzero = {0.f, 0.f, 0.f, 0.f};
  f32x4 acc[4][4];
  #pragma unroll
  for (int i = 0; i < 4; ++i)
    #pragma unroll
    for (int j = 0; j < 4; ++j) acc[i][j] = fzero;

  for (int k0 = 0; k0 < K; k0 += 64) {
    __syncthreads();
    #pragma unroll
    for (int i = 0; i < 4; ++i) {
      __builtin_amdgcn_global_load_lds((gas_ptr)(Ag + (size_t)(i * 8) * K),
                                       (las_ptr)&As[(wave * 32 + i * 8) * 64], 16, 0, 0);
      __builtin_amdgcn_global_load_lds((gas_ptr)(Bg + (size_t)(i * 8) * K),
                                       (las_ptr)&Bs[(wave * 32 + i * 8) * 64], 16, 0, 0);
    }
    Ag += 64; Bg += 64;
    __syncthreads();
    #pragma unroll
    for (int kc = 0; kc < 2; ++kc) {
      bf16x8 af[4], bfr[4];
      const int pcg = ((kc * 4 + lh) ^ sw) * 8;   // swizzled column offset
      #pragma unroll
      for (int mt = 0; mt < 4; ++mt)
        af[mt] = *(const bf16x8*)&As[(wm * 64 + mt * 16 + ll) * 64 + pcg];
      #pragma unroll
      for (int nt = 0; nt < 4; ++nt)
        bfr[nt] = *(const bf16x8*)&Bs[(wn * 64 + nt * 16 + ll) * 64 + pcg];
      #pragma unroll
      for (int mt = 0; mt < 4; ++mt)
        #pragma unroll
        for (int nt = 0; nt < 4; ++nt)
          acc[mt][nt] = __builtin_amdgcn_mfma_f32_16x16x32_bf16(af[mt], bfr[nt], acc[mt][nt], 0, 0, 0);
    }
  }
  // epilogue; verified C/D layout: col = lane&15, row = (lane>>4)*4 + reg
  #pragma unroll
  for (int mt = 0; mt < 4; ++mt) {
    const int row = m0 + wm * 64 + mt * 16 + lh * 4;
    #pragma unroll
    for (int nt = 0; nt < 4; ++nt) {
      const int col = n0 + wn * 64 + nt * 16 + ll;
      #pragma unroll
      for (int rg = 0; rg < 4; ++rg) {
        const float c = acc[mt][nt][rg];
        const size_t idx = (size_t)(row + rg) * N + col;
        if constexpr (EPI == 0) {
          ((short*)Cv)[idx] = f2bf(c);
        } else if constexpr (EPI == 1) {
          ((float*)Cv)[idx] = c + ((const float*)aux)[idx];
        } else if constexpr (EPI == 2) {
          float g = 0.5f * c * (1.0f + erff(c * 0.70710678118654752f));
          ((short*)Cv)[idx] = f2bf(g);
        } else {
          float g = bf2f(((short*)Cv)[idx]);
          ((short*)Cv)[idx] = f2bf(c * g);
        }
      }
    }
  }
}

// ---------------- flash attention ----------------
#define CEXP 0.12752682475470602f   // log2(e)/sqrt(128)
__global__ __launch_bounds__(256, 2) void k_flash(const short* __restrict__ qkv,
                                                  const short* __restrict__ vt,
                                                  short* __restrict__ attn) {
  __shared__ short Kt[64][136];
  __shared__ short VtT[128][72];
  __shared__ short Pt[4][32][72];
  const int qt = blockIdx.x, bh = blockIdx.y;
  const int b = bh >> 4, h = bh & 15;
  const int q0 = qt << 7;
  const int tid = threadIdx.x, wave = tid >> 6, lane = tid & 63;
  const int ll = lane & 15, lh = lane >> 4;
  const short* qbase = qkv + (size_t)b * S_ * QKVN + h * DH_;
  const short* kbase = qbase + E_;
  const short* vbase = vt + (size_t)bh * DH_ * S_;

  bf16x8 qf[2][4];
  #pragma unroll
  for (int mt = 0; mt < 2; ++mt) {
    const short* qr = qbase + (size_t)(q0 + wave * 32 + mt * 16 + ll) * QKVN;
    #pragma unroll
    for (int kc = 0; kc < 4; ++kc) qf[mt][kc] = *(const bf16x8*)(qr + kc * 32 + lh * 8);
  }

  const f32x4 fzero = {0.f, 0.f, 0.f, 0.f};
  float m_i[2][4], l_i[2][4];
  f32x4 oacc[2][8];
  #pragma unroll
  for (int mt = 0; mt < 2; ++mt) {
    #pragma unroll
    for (int rg = 0; rg < 4; ++rg) { m_i[mt][rg] = -1e30f; l_i[mt][rg] = 0.f; }
    #pragma unroll
    for (int n8 = 0; n8 < 8; ++n8) oacc[mt][n8] = fzero;
  }

  const int nkt = (q0 + 128) >> 6;
  for (int kt = 0; kt < nkt; ++kt) {
    const int k0 = kt << 6;
    __syncthreads();
    #pragma unroll
    for (int p = 0; p < 4; ++p) {
      int idx = p * 256 + tid;
      int r = idx >> 4, c0 = (idx & 15) << 3;
      *(s16x8*)&Kt[r][c0] = *(const s16x8*)(kbase + (size_t)(k0 + r) * QKVN + c0);
      int dh = idx >> 3, kk = (idx & 7) << 3;
      *(s16x8*)&VtT[dh][kk] = *(const s16x8*)(vbase + (size_t)dh * S_ + k0 + kk);
    }
    __syncthreads();

    f32x4 sc[2][4];
    #pragma unroll
    for (int mt = 0; mt < 2; ++mt)
      #pragma unroll
      for (int nt = 0; nt < 4; ++nt) sc[mt][nt] = fzero;
    #pragma unroll
    for (int kc = 0; kc < 4; ++kc) {
      bf16x8 kb[4];
      #pragma unroll
      for (int nt = 0; nt < 4; ++nt)
        kb[nt] = *(const bf16x8*)&Kt[nt * 16 + ll][kc * 32 + lh * 8];
      #pragma unroll
      for (int mt = 0; mt < 2; ++mt)
        #pragma unroll
        for (int nt = 0; nt < 4; ++nt)
          sc[mt][nt] = __builtin_amdgcn_mfma_f32_16x16x32_bf16(qf[mt][kc], kb[nt], sc[mt][nt], 0, 0, 0);
    }

    if (k0 + 63 > q0) {
      #pragma unroll
      for (int mt = 0; mt < 2; ++mt)
        #pragma unroll
        for (int nt = 0; nt < 4; ++nt)
          #pragma unroll
          for (int rg = 0; rg < 4; ++rg) {
            int kidx = k0 + nt * 16 + ll;
            int qidx = q0 + wave * 32 + mt * 16 + lh * 4 + rg;
            if (kidx > qidx) sc[mt][nt][rg] = -1e30f;
          }
    }

    #pragma unroll
    for (int mt = 0; mt < 2; ++mt)
      #pragma unroll
      for (int rg = 0; rg < 4; ++rg) {
        float mx = fmaxf(fmaxf(sc[mt][0][rg], sc[mt][1][rg]),
                         fmaxf(sc[mt][2][rg], sc[mt][3][rg]));
        #pragma unroll
        for (int off = 1; off < 16; off <<= 1) mx = fmaxf(mx, __shfl_xor(mx, off, 64));
        float mn = fmaxf(m_i[mt][rg], mx);
        float al = exp2f((m_i[mt][rg] - mn) * CEXP);
        m_i[mt][rg] = mn;
        float rsum = 0.f;
        #pragma unroll
        for (int nt = 0; nt < 4; ++nt) {
          float pv = exp2f((sc[mt][nt][rg] - mn) * CEXP);
          sc[mt][nt][rg] = pv;
          rsum += pv;
        }
        #pragma unroll
        for (int off = 1; off < 16; off <<= 1) rsum += __shfl_xor(rsum, off, 64);
        l_i[mt][rg] = l_i[mt][rg] * al + rsum;
        #pragma unroll
        for (int n8 = 0; n8 < 8; ++n8) oacc[mt][n8][rg] *= al;
      }

    #pragma unroll
    for (int mt = 0; mt < 2; ++mt)
      #pragma unroll
      for (int nt = 0; nt < 4; ++nt)
        #pragma unroll
        for (int rg = 0; rg < 4; ++rg)
          Pt[wave][mt * 16 + lh * 4 + rg][nt * 16 + ll] = f2bf(sc[mt][nt][rg]);

    #pragma unroll
    for (int kc2 = 0; kc2 < 2; ++kc2) {
      bf16x8 pa[2];
      #pragma unroll
      for (int mt = 0; mt < 2; ++mt)
        pa[mt] = *(const bf16x8*)&Pt[wave][mt * 16 + ll][kc2 * 32 + lh * 8];
      #pragma unroll
      for (int n8 = 0; n8 < 8; ++n8) {
        bf16x8 vb = *(const bf16x8*)&VtT[n8 * 16 + ll][kc2 * 32 + lh * 8];
        #pragma unroll
        for (int mt = 0; mt < 2; ++mt)
          oacc[mt][n8] = __builtin_amdgcn_mfma_f32_16x16x32_bf16(pa[mt], vb, oacc[mt][n8], 0, 0, 0);
      }
    }
  }

  short* ab = attn + (size_t)(b * S_) * E_ + h * DH_;
  #pragma unroll
  for (int mt = 0; mt < 2; ++mt) {
    const int row = q0 + wave * 32 + mt * 16 + lh * 4;
    #pragma unroll
    for (int n8 = 0; n8 < 8; ++n8) {
      const int col = n8 * 16 + ll;
      #pragma unroll
      for (int rg = 0; rg < 4; ++rg)
        ab[(size_t)(row + rg) * E_ + col] = f2bf(oacc[mt][n8][rg] / l_i[mt][rg]);
    }
  }
}

// ---------------- launch ----------------
// Workspace plan (192 MiB; single stream => lifetime-disjoint aliasing is safe):
//   W slot   [ 33,554,432 B]  each weight transposed here right before its GEMM
//   big slot [134,217,728 B]  phase 1: QKV | VT; phase 2: Hb
//   act slot [ 33,554,432 B]  Y1 -> ATTN -> Y2
//   X2 (fp32 residual stream) lives in d_out, overwritten by the final GEMM.
extern "C" void kernel_launch(void* const* d_in, const int* in_sizes, int n_in,
                              void* d_out, int out_size, void* d_ws, size_t ws_size,
                              hipStream_t stream) {
  (void)in_sizes; (void)n_in; (void)out_size; (void)ws_size;
  const float* x      = (const float*)d_in[0];
  const float* g_attn = (const float*)d_in[1];
  const float* g_ffn  = (const float*)d_in[2];
  const float* wq     = (const float*)d_in[3];
  const float* wk     = (const float*)d_in[4];
  const float* wv     = (const float*)d_in[5];
  const float* wo     = (const float*)d_in[6];
  const float* wg     = (const float*)d_in[7];
  const float* wl     = (const float*)d_in[8];
  const float* wout   = (const float*)d_in[9];
  const int*   pos    = (const int*)d_in[10];

  char* wsb = (char*)d_ws;
  short* W    = (short*)wsb;
  short* BIG  = (short*)(wsb + (size_t)33554432);
  short* ACT  = (short*)(wsb + (size_t)33554432 + 134217728);

  short* QKV  = BIG;
  short* VT   = BIG + (size_t)NTOK * QKVN;
  short* Hb   = BIG;
  short* Y1   = ACT;
  short* ATTN = ACT;
  short* Y2   = ACT;
  float* X2   = (float*)d_out;

  const dim3 blk(256);

  k_transpose_f32_bf16<<<dim3(64, 64), blk, 0, stream>>>(wq, W,                   2048, 2048);
  k_transpose_f32_bf16<<<dim3(64, 64), blk, 0, stream>>>(wk, W + 2048 * 2048,     2048, 2048);
  k_transpose_f32_bf16<<<dim3(64, 64), blk, 0, stream>>>(wv, W + 2 * 2048 * 2048, 2048, 2048);

  k_rms_rope<<<NTOK, blk, 0, stream>>>(x, g_attn, pos, Y1);
  k_gemm<0><<<dim3(QKVN / 128, NTOK / 128), blk, 0, stream>>>(Y1, W, QKV, nullptr, NTOK, QKVN, E_);
  k_transpose_v<<<dim3(S_ / 32, DH_ / 32, B_ * H_), blk, 0, stream>>>(QKV, VT);
  k_flash<<<dim3(S_ / 128, B_ * H_), blk, 0, stream>>>(QKV, VT, ATTN);

  k_transpose_f32_bf16<<<dim3(64, 64), blk, 0, stream>>>(wo, W, 2048, 2048);
  k_gemm<1><<<dim3(E_ / 128, NTOK / 128), blk, 0, stream>>>(ATTN, W, X2, x, NTOK, E_, E_);

  k_rms<<<NTOK, blk, 0, stream>>>(X2, g_ffn, Y2);

  k_transpose_f32_bf16<<<dim3(256, 64), blk, 0, stream>>>(wg, W, 2048, 8192);
  k_gemm<2><<<dim3(F_ / 128, NTOK / 128), blk, 0, stream>>>(Y2, W, Hb, nullptr, NTOK, F_, E_);
  k_transpose_f32_bf16<<<dim3(256, 64), blk, 0, stream>>>(wl, W, 2048, 8192);
  k_gemm<3><<<dim3(F_ / 128, NTOK / 128), blk, 0, stream>>>(Y2, W, Hb, nullptr, NTOK, F_, E_);
  k_transpose_f32_bf16<<<dim3(64, 256), blk, 0, stream>>>(wout, W, 8192, 2048);
  k_gemm<1><<<dim3(E_ / 128, NTOK / 128), blk, 0, stream>>>(Hb, W, d_out, X2, NTOK, E_, F_);
}